// Round 1
// baseline (591.754 us; speedup 1.0000x reference)
//
#include <hip/hip_runtime.h>
#include <hip/hip_bf16.h>

// CRF NLL: B=512, S=1024, T=64.
// Inputs: emissions f32 (B,S,T), tags i32 (B,S), mask i32 (B,S),
//         start f32 (T), end f32 (T), trans f32 (T,T).
// Output: scalar f32 = -(sum_b ll_b) / (sum_b len_b)

#define S_LEN 1024
#define T_TAGS 64
#define LOG2E 1.4426950408889634f
#define LN2   0.6931471805599453f

__device__ __forceinline__ float rfl_f32(float x) {
  return __uint_as_float(__builtin_amdgcn_readfirstlane(__float_as_uint(x)));
}

__global__ __launch_bounds__(64) void crf_batch(
    const float* __restrict__ em, const int* __restrict__ tags,
    const int* __restrict__ mask, const float* __restrict__ start,
    const float* __restrict__ endt, const float* __restrict__ trans,
    float* __restrict__ ll_out, int* __restrict__ len_out) {
  const int b = blockIdx.x;
  const int l = threadIdx.x;  // 0..63, lane == column j
  const float* emb = em + (size_t)b * S_LEN * T_TAGS;
  const int* tg = tags + (size_t)b * S_LEN;

  // ---- length = sum(mask[b,:]) (mask is a contiguous prefix of ones) ----
  int lenp = 0;
  const int4* mk4 = (const int4*)(mask + (size_t)b * S_LEN);
  #pragma unroll
  for (int c = 0; c < 4; ++c) {
    int4 v = mk4[l + 64 * c];
    lenp += v.x + v.y + v.z + v.w;
  }
  #pragma unroll
  for (int d = 1; d < 64; d <<= 1) lenp += __shfl_xor(lenp, d);
  const int len = lenp;  // in [512, 1024]

  // ---- numerator (gold-path score), lane-parallel over s ----
  float nump = 0.f;
  for (int s = 1 + l; s < len; s += 64) {
    int tp = tg[s - 1], tc = tg[s];
    nump += trans[tp * T_TAGS + tc] + emb[(size_t)s * T_TAGS + tc];
  }
  #pragma unroll
  for (int d = 1; d < 64; d <<= 1) nump += __shfl_xor(nump, d);
  const int tg0 = tg[0];
  const float num = nump + start[tg0] + emb[tg0] + endt[tg[len - 1]];

  // ---- E columns in registers: e[i] = 2^(trans[i][l] * log2e) = exp(trans[i][l]) ----
  float e[T_TAGS];
  #pragma unroll
  for (int i = 0; i < T_TAGS; ++i)
    e[i] = __builtin_amdgcn_exp2f(trans[i * T_TAGS + l] * LOG2E);

  // ---- forward scan ----
  float alpha = start[l] + emb[l];  // s = 0

  __shared__ float pbuf[T_TAGS];

  // em prefetch, distance 2 (len >= 512 so s=1,2 always valid & needed)
  float emA = emb[(size_t)1 * T_TAGS + l];
  float emB = emb[(size_t)2 * T_TAGS + l];

  for (int s = 1; s < len; ++s) {
    // m: any value within ~±30 of max(alpha) is numerically safe; lane0's alpha
    // is within the per-step spread (<= ~12) of the max. Avoids a 6-op reduce.
    const float m = rfl_f32(alpha);
    const float p = __builtin_amdgcn_exp2f((alpha - m) * LOG2E);
    pbuf[l] = p;
    asm volatile("s_waitcnt lgkmcnt(0)" ::: "memory");  // write visible to all lanes (same wave)

    float acc0 = 0.f, acc1 = 0.f, acc2 = 0.f, acc3 = 0.f;
    const float4* p4 = (const float4*)pbuf;
    #pragma unroll
    for (int c = 0; c < 16; ++c) {
      float4 pc = p4[c];  // broadcast ds_read_b128
      acc0 = fmaf(pc.x, e[4 * c + 0], acc0);
      acc1 = fmaf(pc.y, e[4 * c + 1], acc1);
      acc2 = fmaf(pc.z, e[4 * c + 2], acc2);
      acc3 = fmaf(pc.w, e[4 * c + 3], acc3);
    }
    const float v = (acc0 + acc1) + (acc2 + acc3);

    const float emcur = emA;
    emA = emB;
    const int snext = (s + 2 < len) ? (s + 2) : (len - 1);
    emB = emb[(size_t)snext * T_TAGS + l];

    // alpha_new[j] = m + ln(v_j) + em[s][j]
    alpha = fmaf(__builtin_amdgcn_logf(v) , LN2, emcur) + m;
  }

  // ---- denominator: exact lse over lanes of (alpha + end) ----
  float fin = alpha + endt[l];
  float mx = fin;
  #pragma unroll
  for (int d = 1; d < 64; d <<= 1) mx = fmaxf(mx, __shfl_xor(mx, d));
  float ex = __builtin_amdgcn_exp2f((fin - mx) * LOG2E);
  #pragma unroll
  for (int d = 1; d < 64; d <<= 1) ex += __shfl_xor(ex, d);
  const float den = fmaf(__builtin_amdgcn_logf(ex), LN2, mx);

  if (l == 0) {
    ll_out[b] = num - den;
    len_out[b] = len;
  }
}

__global__ __launch_bounds__(512) void crf_reduce(
    const float* __restrict__ ll, const int* __restrict__ lens, int nb,
    float* __restrict__ out) {
  const int t = threadIdx.x;
  double sll = 0.0, sln = 0.0;
  if (t < nb) { sll = (double)ll[t]; sln = (double)lens[t]; }
  #pragma unroll
  for (int d = 1; d < 64; d <<= 1) {
    sll += __shfl_xor(sll, d);
    sln += __shfl_xor(sln, d);
  }
  __shared__ double wa[8], wc[8];
  const int w = t >> 6;
  if ((t & 63) == 0) { wa[w] = sll; wc[w] = sln; }
  __syncthreads();
  if (t == 0) {
    double A = 0.0, C = 0.0;
    #pragma unroll
    for (int i = 0; i < 8; ++i) { A += wa[i]; C += wc[i]; }
    out[0] = (float)(-(A / C));
  }
}

extern "C" void kernel_launch(void* const* d_in, const int* in_sizes, int n_in,
                              void* d_out, int out_size, void* d_ws, size_t ws_size,
                              hipStream_t stream) {
  const float* em    = (const float*)d_in[0];
  const int*   tags  = (const int*)d_in[1];
  const int*   mask  = (const int*)d_in[2];
  const float* start = (const float*)d_in[3];
  const float* endt  = (const float*)d_in[4];
  const float* trans = (const float*)d_in[5];
  float* out = (float*)d_out;

  const int B = in_sizes[1] / S_LEN;  // 512

  float* ll  = (float*)d_ws;
  int*   len = (int*)(ll + B);

  crf_batch<<<dim3(B), dim3(64), 0, stream>>>(em, tags, mask, start, endt, trans, ll, len);
  crf_reduce<<<dim3(1), dim3(512), 0, stream>>>(ll, len, B, out);
}